// Round 1
// baseline (272.889 us; speedup 1.0000x reference)
//
#include <hip/hip_runtime.h>
#include <hip/hip_fp16.h>

// ResidualDenoiser: 4 chained GEMMs + BN/ReLU + ragged segment softmax.
// Activations live in one persistent fp16 buffer H[8192][3328] laid out
// [A3 | A2 | A1 | A0=x] so each layer's concatenated input is H + colOff.
//   layer0: in H+3072 (K= 256) -> out cols 2048:3072
//   layer1: in H+2048 (K=1280) -> out cols 1024:2048
//   layer2: in H+1024 (K=2304) -> out cols    0:1024
//   layer3: in H+0    (K=3328) -> fp32 logits to d_out, then segment softmax.

#define LDH 3328
#define NROWS 8192

typedef _Float16 f16x8 __attribute__((ext_vector_type(8)));
typedef _Float16 f16x4 __attribute__((ext_vector_type(4)));
typedef float f32x4 __attribute__((ext_vector_type(4)));

__constant__ int c_bnd[11] = {0, 2, 5, 10, 18, 31, 52, 86, 141, 230, 256};

// async global->LDS, 16B per lane; LDS dest is wave-uniform base + lane*16.
__device__ __forceinline__ void async_cp16(const _Float16* g, _Float16* l) {
  __builtin_amdgcn_global_load_lds(
      (__attribute__((address_space(1))) void*)g,
      (__attribute__((address_space(3))) void*)l, 16, 0, 0);
}

__device__ __forceinline__ _Float16 f2h(float f) { return (_Float16)f; }

// ---------------------------------------------------------------------------
// fp32 -> fp16 weight convert (contiguous)
__global__ void cvt_kernel(const float* __restrict__ src,
                           _Float16* __restrict__ dst, int n4) {
  int i = blockIdx.x * blockDim.x + threadIdx.x;
  if (i >= n4) return;
  const float4 v = *(const float4*)&src[(size_t)i * 4];
  f16x4 h = {f2h(v.x), f2h(v.y), f2h(v.z), f2h(v.w)};
  *(f16x4*)&dst[(size_t)i * 4] = h;
}

// x [8192,256] fp32 -> H[:, 3072:3328] fp16
__global__ void stagex_kernel(const float* __restrict__ x,
                              _Float16* __restrict__ H) {
  int i = blockIdx.x * blockDim.x + threadIdx.x;  // over 8192*64
  int row = i >> 6;
  int c = (i & 63) * 4;
  const float4 v = *(const float4*)&x[(size_t)row * 256 + c];
  f16x4 h = {f2h(v.x), f2h(v.y), f2h(v.z), f2h(v.w)};
  *(f16x4*)&H[(size_t)row * LDH + 3072 + c] = h;
}

// ---------------------------------------------------------------------------
// C[M,N] = A[M,K] @ W[N,K]^T ; BM=BN=128, BK=64, 4 waves (2x2), 16x16x32 f16.
// FUSE=1: out fp16 = relu(acc*alpha + beta) into H (stride LDH, + outOff)
// FUSE=0: out fp32 = acc + bias into outF (stride ldF)
template <int FUSE>
__launch_bounds__(256, 2) __global__
void gemm_kernel(const _Float16* __restrict__ A, int ldA, int K,
                 const _Float16* __restrict__ W,
                 const float* __restrict__ bias, const float* __restrict__ g,
                 const float* __restrict__ be, const float* __restrict__ rm,
                 const float* __restrict__ rv,
                 _Float16* __restrict__ outH, int outOff,
                 float* __restrict__ outF, int ldF) {
  __shared__ _Float16 Alds[128 * 64];
  __shared__ _Float16 Blds[128 * 64];

  const int tid = threadIdx.x;
  const int lane = tid & 63;
  const int wave = tid >> 6;          // 0..3
  const int wr = wave >> 1;           // wave row (0/1) -> 64 rows
  const int wc = wave & 1;            // wave col (0/1) -> 64 cols
  const int row0 = blockIdx.x * 128;  // M block
  const int col0 = blockIdx.y * 128;  // N block
  // staging lane decomposition: 8 rows x 8 chunks(16B) per wave-instruction
  const int lr = lane >> 3;  // row within 8-row group
  const int ls = lane & 7;   // lds slot within row
  const int lc = ls ^ lr;    // XOR-swizzle: global chunk fetched into slot ls
  // fragment lane decomposition (16x16x32 MFMA)
  const int fr = lane & 15;  // m (A) / n (B) index
  const int q = lane >> 4;   // quad: k = q*8 + j

  f32x4 acc[4][4] = {};

  for (int k0 = 0; k0 < K; k0 += 64) {
    __syncthreads();  // previous-iter consumers done before overwrite
#pragma unroll
    for (int it = 0; it < 4; ++it) {
      const int rl = it * 32 + wave * 8;  // local tile row base
      const _Float16* ga =
          A + (size_t)(row0 + rl + lr) * ldA + k0 + lc * 8;
      async_cp16(ga, &Alds[rl * 64]);
      const _Float16* gb =
          W + (size_t)(col0 + rl + lr) * K + k0 + lc * 8;
      async_cp16(gb, &Blds[rl * 64]);
    }
    __syncthreads();  // drains vmcnt: staging complete

#pragma unroll
    for (int kq = 0; kq < 2; ++kq) {
      f16x8 av[4], bv[4];
#pragma unroll
      for (int t = 0; t < 4; ++t) {
        const int ra = wr * 64 + t * 16 + fr;
        av[t] = *(const f16x8*)&Alds[ra * 64 + (((q + 4 * kq) ^ (ra & 7)) * 8)];
        const int rb = wc * 64 + t * 16 + fr;
        bv[t] = *(const f16x8*)&Blds[rb * 64 + (((q + 4 * kq) ^ (rb & 7)) * 8)];
      }
#pragma unroll
      for (int tm = 0; tm < 4; ++tm)
#pragma unroll
        for (int tn = 0; tn < 4; ++tn)
          acc[tm][tn] = __builtin_amdgcn_mfma_f32_16x16x32_f16(
              av[tm], bv[tn], acc[tm][tn], 0, 0, 0);
    }
  }

  // Epilogue. C/D layout: col = lane&15, row = (lane>>4)*4 + reg.
#pragma unroll
  for (int tn = 0; tn < 4; ++tn) {
    const int n = col0 + wc * 64 + tn * 16 + fr;
    if constexpr (FUSE == 1) {
      const float alpha = g[n] * rsqrtf(rv[n] + 1e-5f);
      const float beta = (bias[n] - rm[n]) * alpha + be[n];
#pragma unroll
      for (int tm = 0; tm < 4; ++tm) {
        const int rbase = row0 + wr * 64 + tm * 16 + q * 4;
#pragma unroll
        for (int r = 0; r < 4; ++r) {
          float v = acc[tm][tn][r] * alpha + beta;
          v = fmaxf(v, 0.0f);
          outH[(size_t)(rbase + r) * LDH + outOff + n] = f2h(v);
        }
      }
    } else {
      const float bb = bias[n];
#pragma unroll
      for (int tm = 0; tm < 4; ++tm) {
        const int rbase = row0 + wr * 64 + tm * 16 + q * 4;
#pragma unroll
        for (int r = 0; r < 4; ++r)
          outF[(size_t)(rbase + r) * ldF + n] = acc[tm][tn][r] + bb;
      }
    }
  }
}

// ---------------------------------------------------------------------------
// ragged segment softmax, in place on out[8192][256]; 1 wave per row.
__global__ void segsoftmax_kernel(float* __restrict__ out,
                                  const int* __restrict__ segids) {
  __shared__ float vals[256];
  __shared__ float red[10];
  const int row = blockIdx.x;
  const int l = threadIdx.x;  // 0..63
  float4 v = *(float4*)&out[(size_t)row * 256 + l * 4];
  *(float4*)&vals[l * 4] = v;
  __syncthreads();
  if (l < 10) {
    float m = -1e30f;
    for (int j = c_bnd[l]; j < c_bnd[l + 1]; ++j) m = fmaxf(m, vals[j]);
    red[l] = m;
  }
  __syncthreads();
  const int4 s4 = *(const int4*)&segids[l * 4];
  float4 e;
  e.x = expf(v.x - red[s4.x]);
  e.y = expf(v.y - red[s4.y]);
  e.z = expf(v.z - red[s4.z]);
  e.w = expf(v.w - red[s4.w]);
  *(float4*)&vals[l * 4] = e;
  __syncthreads();
  if (l < 10) {
    float s = 0.0f;
    for (int j = c_bnd[l]; j < c_bnd[l + 1]; ++j) s += vals[j];
    red[l] = s;
  }
  __syncthreads();
  float4 o;
  o.x = e.x / red[s4.x];
  o.y = e.y / red[s4.y];
  o.z = e.z / red[s4.z];
  o.w = e.w / red[s4.w];
  *(float4*)&out[(size_t)row * 256 + l * 4] = o;
}

// ---------------------------------------------------------------------------
extern "C" void kernel_launch(void* const* d_in, const int* in_sizes, int n_in,
                              void* d_out, int out_size, void* d_ws,
                              size_t ws_size, hipStream_t stream) {
  const float* x = (const float*)d_in[0];
  const float* W0 = (const float*)d_in[1];
  const float* b0 = (const float*)d_in[2];
  const float* g0 = (const float*)d_in[3];
  const float* be0 = (const float*)d_in[4];
  const float* rm0 = (const float*)d_in[5];
  const float* rv0 = (const float*)d_in[6];
  const float* W1 = (const float*)d_in[7];
  const float* b1 = (const float*)d_in[8];
  const float* g1 = (const float*)d_in[9];
  const float* be1 = (const float*)d_in[10];
  const float* rm1 = (const float*)d_in[11];
  const float* rv1 = (const float*)d_in[12];
  const float* W2 = (const float*)d_in[13];
  const float* b2 = (const float*)d_in[14];
  const float* g2 = (const float*)d_in[15];
  const float* be2 = (const float*)d_in[16];
  const float* rm2 = (const float*)d_in[17];
  const float* rv2 = (const float*)d_in[18];
  const float* W3 = (const float*)d_in[19];
  const float* b3 = (const float*)d_in[20];
  const int* seg = (const int*)d_in[21];
  float* out = (float*)d_out;

  // workspace layout (fp16): H[8192*3328] | Wh0 | Wh1 | Wh2 | Wh3  (~64.1 MB)
  _Float16* H = (_Float16*)d_ws;
  size_t off = (size_t)NROWS * LDH;
  _Float16* Wh0 = H + off; off += 1024 * 256;
  _Float16* Wh1 = H + off; off += 1024 * 1280;
  _Float16* Wh2 = H + off; off += 1024 * 2304;
  _Float16* Wh3 = H + off;

  cvt_kernel<<<256, 256, 0, stream>>>(W0, Wh0, 65536);
  cvt_kernel<<<1280, 256, 0, stream>>>(W1, Wh1, 327680);
  cvt_kernel<<<2304, 256, 0, stream>>>(W2, Wh2, 589824);
  cvt_kernel<<<832, 256, 0, stream>>>(W3, Wh3, 212992);
  stagex_kernel<<<2048, 256, 0, stream>>>(x, H);

  dim3 blk(256);
  gemm_kernel<1><<<dim3(64, 8), blk, 0, stream>>>(
      H + 3072, LDH, 256, Wh0, b0, g0, be0, rm0, rv0, H, 2048, nullptr, 0);
  gemm_kernel<1><<<dim3(64, 8), blk, 0, stream>>>(
      H + 2048, LDH, 1280, Wh1, b1, g1, be1, rm1, rv1, H, 1024, nullptr, 0);
  gemm_kernel<1><<<dim3(64, 8), blk, 0, stream>>>(
      H + 1024, LDH, 2304, Wh2, b2, g2, be2, rm2, rv2, H, 0, nullptr, 0);
  gemm_kernel<0><<<dim3(64, 2), blk, 0, stream>>>(
      H, LDH, 3328, Wh3, b3, nullptr, nullptr, nullptr, nullptr, nullptr, 0,
      out, 256);
  segsoftmax_kernel<<<8192, 64, 0, stream>>>(out, seg);
}

// Round 2
// 254.331 us; speedup vs baseline: 1.0730x; 1.0730x over previous
//
#include <hip/hip_runtime.h>
#include <hip/hip_fp16.h>

// ResidualDenoiser: 4 chained GEMMs + BN/ReLU + ragged segment softmax.
// Activations live in one persistent fp16 buffer H[8192][3328] laid out
// [A3 | A2 | A1 | A0=x] so each layer's concatenated input is H + colOff.
//   layer0: in H+3072 (K= 256) -> out cols 2048:3072
//   layer1: in H+2048 (K=1280) -> out cols 1024:2048
//   layer2: in H+1024 (K=2304) -> out cols    0:1024
//   layer3: in H+0    (K=3328) -> split-K=4, atomicAdd fp32 into d_out
//           (pre-initialized with bias), then in-place segment softmax.

#define LDH 3328
#define NROWS 8192

typedef _Float16 f16x8 __attribute__((ext_vector_type(8)));
typedef _Float16 f16x4 __attribute__((ext_vector_type(4)));
typedef float f32x4 __attribute__((ext_vector_type(4)));

__constant__ int c_bnd[11] = {0, 2, 5, 10, 18, 31, 52, 86, 141, 230, 256};

// async global->LDS, 16B per lane; LDS dest is wave-uniform base + lane*16.
__device__ __forceinline__ void async_cp16(const _Float16* g, _Float16* l) {
  __builtin_amdgcn_global_load_lds(
      (__attribute__((address_space(1))) void*)g,
      (__attribute__((address_space(3))) void*)l, 16, 0, 0);
}

__device__ __forceinline__ _Float16 f2h(float f) { return (_Float16)f; }

// ---------------------------------------------------------------------------
// all-weights fp32 -> fp16 convert, virtually concatenated (counts in float4)
__global__ void cvt_all_kernel(const float* __restrict__ s0,
                               const float* __restrict__ s1,
                               const float* __restrict__ s2,
                               const float* __restrict__ s3,
                               _Float16* __restrict__ d0,
                               _Float16* __restrict__ d1,
                               _Float16* __restrict__ d2,
                               _Float16* __restrict__ d3,
                               int n0, int n1, int n2, int n3) {
  int i = blockIdx.x * blockDim.x + threadIdx.x;
  const float* s;
  _Float16* d;
  if (i < n0) {
    s = s0; d = d0;
  } else if (i < n1) {
    s = s1 - (size_t)n0 * 4; d = d1 - (size_t)n0 * 4;
  } else if (i < n2) {
    s = s2 - (size_t)n1 * 4; d = d2 - (size_t)n1 * 4;
  } else if (i < n3) {
    s = s3 - (size_t)n2 * 4; d = d3 - (size_t)n2 * 4;
  } else {
    return;
  }
  const float4 v = *(const float4*)&s[(size_t)i * 4];
  f16x4 h = {f2h(v.x), f2h(v.y), f2h(v.z), f2h(v.w)};
  *(f16x4*)&d[(size_t)i * 4] = h;
}

// x [8192,256] fp32 -> H[:, 3072:3328] fp16
__global__ void stagex_kernel(const float* __restrict__ x,
                              _Float16* __restrict__ H) {
  int i = blockIdx.x * blockDim.x + threadIdx.x;  // over 8192*64
  int row = i >> 6;
  int c = (i & 63) * 4;
  const float4 v = *(const float4*)&x[(size_t)row * 256 + c];
  f16x4 h = {f2h(v.x), f2h(v.y), f2h(v.z), f2h(v.w)};
  *(f16x4*)&H[(size_t)row * LDH + 3072 + c] = h;
}

// out[8192][256] = broadcast bias (split-K partials atomicAdd on top)
__global__ void init_out_kernel(float* __restrict__ out,
                                const float* __restrict__ bias) {
  int i = blockIdx.x * blockDim.x + threadIdx.x;  // over 8192*64
  int c = (i & 63) * 4;
  const float4 b = *(const float4*)&bias[c];
  *(float4*)&out[(size_t)i * 4] = b;
}

// ---------------------------------------------------------------------------
// C[M,N] = A[M,K] @ W[N,K]^T ; BM=BN=128, BK=64, 4 waves (2x2), 16x16x32 f16.
// FUSE=1: out fp16 = relu(acc*alpha + beta) into H (stride LDH, + outOff)
// FUSE=0: atomicAdd fp32 partial into outF (stride ldF); bias pre-applied.
template <int FUSE>
__launch_bounds__(256, 4) __global__
void gemm_kernel(const _Float16* __restrict__ A, int ldA, int K,
                 int kBeg, int kEnd,
                 const _Float16* __restrict__ W,
                 const float* __restrict__ bias, const float* __restrict__ g,
                 const float* __restrict__ be, const float* __restrict__ rm,
                 const float* __restrict__ rv,
                 _Float16* __restrict__ outH, int outOff,
                 float* __restrict__ outF, int ldF, int nColBlk) {
  __shared__ _Float16 Alds[128 * 64];
  __shared__ _Float16 Blds[128 * 64];

  const int tid = threadIdx.x;
  const int lane = tid & 63;
  const int wave = tid >> 6;          // 0..3
  const int wr = wave >> 1;           // wave row (0/1) -> 64 rows
  const int wc = wave & 1;            // wave col (0/1) -> 64 cols
  const int row0 = blockIdx.x * 128;  // M block
  const int cb = blockIdx.y % nColBlk;
  const int ks = blockIdx.y / nColBlk;  // split-K index
  const int col0 = cb * 128;
  const int k0b = kBeg + ks * (kEnd - kBeg);
  const int k0e = k0b + (kEnd - kBeg);
  // staging lane decomposition: 8 rows x 8 chunks(16B) per wave-instruction
  const int lr = lane >> 3;  // row within 8-row group
  const int ls = lane & 7;   // lds slot within row
  const int lc = ls ^ lr;    // XOR-swizzle: global chunk fetched into slot ls
  // fragment lane decomposition (16x16x32 MFMA)
  const int fr = lane & 15;  // m (A) / n (B) index
  const int q = lane >> 4;   // quad: k = q*8 + j

  f32x4 acc[4][4] = {};

  for (int k0 = k0b; k0 < k0e; k0 += 64) {
    __syncthreads();  // previous-iter consumers done before overwrite
#pragma unroll
    for (int it = 0; it < 4; ++it) {
      const int rl = it * 32 + wave * 8;  // local tile row base
      const _Float16* ga =
          A + (size_t)(row0 + rl + lr) * ldA + k0 + lc * 8;
      async_cp16(ga, &Alds[rl * 64]);
      const _Float16* gb =
          W + (size_t)(col0 + rl + lr) * K + k0 + lc * 8;
      async_cp16(gb, &Blds[rl * 64]);
    }
    __syncthreads();  // drains vmcnt: staging complete

#pragma unroll
    for (int kq = 0; kq < 2; ++kq) {
      f16x8 av[4], bv[4];
#pragma unroll
      for (int t = 0; t < 4; ++t) {
        const int ra = wr * 64 + t * 16 + fr;
        av[t] = *(const f16x8*)&Alds[ra * 64 + (((q + 4 * kq) ^ (ra & 7)) * 8)];
        const int rb = wc * 64 + t * 16 + fr;
        bv[t] = *(const f16x8*)&Blds[rb * 64 + (((q + 4 * kq) ^ (rb & 7)) * 8)];
      }
#pragma unroll
      for (int tm = 0; tm < 4; ++tm)
#pragma unroll
        for (int tn = 0; tn < 4; ++tn)
          acc[tm][tn] = __builtin_amdgcn_mfma_f32_16x16x32_f16(
              av[tm], bv[tn], acc[tm][tn], 0, 0, 0);
    }
  }

  // Epilogue. C/D layout: col = lane&15, row = (lane>>4)*4 + reg.
#pragma unroll
  for (int tn = 0; tn < 4; ++tn) {
    const int n = col0 + wc * 64 + tn * 16 + fr;
    if constexpr (FUSE == 1) {
      const float alpha = g[n] * rsqrtf(rv[n] + 1e-5f);
      const float beta = (bias[n] - rm[n]) * alpha + be[n];
#pragma unroll
      for (int tm = 0; tm < 4; ++tm) {
        const int rbase = row0 + wr * 64 + tm * 16 + q * 4;
#pragma unroll
        for (int r = 0; r < 4; ++r) {
          float v = acc[tm][tn][r] * alpha + beta;
          v = fmaxf(v, 0.0f);
          outH[(size_t)(rbase + r) * LDH + outOff + n] = f2h(v);
        }
      }
    } else {
#pragma unroll
      for (int tm = 0; tm < 4; ++tm) {
        const int rbase = row0 + wr * 64 + tm * 16 + q * 4;
#pragma unroll
        for (int r = 0; r < 4; ++r)
          atomicAdd(&outF[(size_t)(rbase + r) * ldF + n], acc[tm][tn][r]);
      }
    }
  }
}

// ---------------------------------------------------------------------------
// ragged segment softmax, in place on out[8192][256]; 1 wave per row.
__global__ void segsoftmax_kernel(float* __restrict__ out,
                                  const int* __restrict__ segids) {
  __shared__ float vals[256];
  __shared__ float red[10];
  const int row = blockIdx.x;
  const int l = threadIdx.x;  // 0..63
  float4 v = *(float4*)&out[(size_t)row * 256 + l * 4];
  *(float4*)&vals[l * 4] = v;
  __syncthreads();
  if (l < 10) {
    float m = -1e30f;
    for (int j = c_bnd[l]; j < c_bnd[l + 1]; ++j) m = fmaxf(m, vals[j]);
    red[l] = m;
  }
  __syncthreads();
  const int4 s4 = *(const int4*)&segids[l * 4];
  float4 e;
  e.x = expf(v.x - red[s4.x]);
  e.y = expf(v.y - red[s4.y]);
  e.z = expf(v.z - red[s4.z]);
  e.w = expf(v.w - red[s4.w]);
  *(float4*)&vals[l * 4] = e;
  __syncthreads();
  if (l < 10) {
    float s = 0.0f;
    for (int j = c_bnd[l]; j < c_bnd[l + 1]; ++j) s += vals[j];
    red[l] = s;
  }
  __syncthreads();
  float4 o;
  o.x = e.x / red[s4.x];
  o.y = e.y / red[s4.y];
  o.z = e.z / red[s4.z];
  o.w = e.w / red[s4.w];
  *(float4*)&out[(size_t)row * 256 + l * 4] = o;
}

// ---------------------------------------------------------------------------
extern "C" void kernel_launch(void* const* d_in, const int* in_sizes, int n_in,
                              void* d_out, int out_size, void* d_ws,
                              size_t ws_size, hipStream_t stream) {
  const float* x = (const float*)d_in[0];
  const float* W0 = (const float*)d_in[1];
  const float* b0 = (const float*)d_in[2];
  const float* g0 = (const float*)d_in[3];
  const float* be0 = (const float*)d_in[4];
  const float* rm0 = (const float*)d_in[5];
  const float* rv0 = (const float*)d_in[6];
  const float* W1 = (const float*)d_in[7];
  const float* b1 = (const float*)d_in[8];
  const float* g1 = (const float*)d_in[9];
  const float* be1 = (const float*)d_in[10];
  const float* rm1 = (const float*)d_in[11];
  const float* rv1 = (const float*)d_in[12];
  const float* W2 = (const float*)d_in[13];
  const float* b2 = (const float*)d_in[14];
  const float* g2 = (const float*)d_in[15];
  const float* be2 = (const float*)d_in[16];
  const float* rm2 = (const float*)d_in[17];
  const float* rv2 = (const float*)d_in[18];
  const float* W3 = (const float*)d_in[19];
  const float* b3 = (const float*)d_in[20];
  const int* seg = (const int*)d_in[21];
  float* out = (float*)d_out;

  // workspace layout (fp16): H[8192*3328] | Wh0 | Wh1 | Wh2 | Wh3  (~64.1 MB)
  _Float16* H = (_Float16*)d_ws;
  size_t off = (size_t)NROWS * LDH;
  _Float16* Wh0 = H + off; off += 1024 * 256;
  _Float16* Wh1 = H + off; off += 1024 * 1280;
  _Float16* Wh2 = H + off; off += 1024 * 2304;
  _Float16* Wh3 = H + off;

  // cumulative float4 counts: W0 65536, W1 327680, W2 589824, W3 212992
  const int n0 = 65536, n1 = n0 + 327680, n2 = n1 + 589824, n3 = n2 + 212992;
  cvt_all_kernel<<<(n3 + 255) / 256, 256, 0, stream>>>(
      W0, W1, W2, W3, Wh0, Wh1, Wh2, Wh3, n0, n1, n2, n3);
  stagex_kernel<<<2048, 256, 0, stream>>>(x, H);
  init_out_kernel<<<2048, 256, 0, stream>>>(out, b3);

  dim3 blk(256);
  gemm_kernel<1><<<dim3(64, 8), blk, 0, stream>>>(
      H + 3072, LDH, 256, 0, 256, Wh0, b0, g0, be0, rm0, rv0, H, 2048,
      nullptr, 0, 8);
  gemm_kernel<1><<<dim3(64, 8), blk, 0, stream>>>(
      H + 2048, LDH, 1280, 0, 1280, Wh1, b1, g1, be1, rm1, rv1, H, 1024,
      nullptr, 0, 8);
  gemm_kernel<1><<<dim3(64, 8), blk, 0, stream>>>(
      H + 1024, LDH, 2304, 0, 2304, Wh2, b2, g2, be2, rm2, rv2, H, 0,
      nullptr, 0, 8);
  // layer3: split-K=4 (each split covers 832 = 13 BK-iters), 2 col blocks
  gemm_kernel<0><<<dim3(64, 8), blk, 0, stream>>>(
      H, LDH, 3328, 0, 832, Wh3, nullptr, nullptr, nullptr, nullptr, nullptr,
      nullptr, 0, out, 256, 2);
  segsoftmax_kernel<<<8192, 64, 0, stream>>>(out, seg);
}